// Round 3
// baseline (480.538 us; speedup 1.0000x reference)
//
#include <hip/hip_runtime.h>
#include <math.h>

#define NB 2048

// pre[] float offsets (folded weights)
#define P_WAL 0
#define P_WBL 1024
#define P_WLBL 2048
#define P_WNAL 3072
#define P_WEFF 4096
#define P_BWA 4160
#define P_BWB 4176
#define P_BWL 4192
#define P_BWN 4208
#define P_C0  4224

// ws float offsets
#define WS_BNPART 4352
#define WS_COEF   135424
#define WS_SMALL  135488
#define WS_BIG_I  463168                  // [2048][2048] f32: intra2T rows [s][16]
#define WS_BIG_V  (463168 + 4194304)      // [2048][2048] f32: v_intra rows [s][16]

typedef float f32x2 __attribute__((ext_vector_type(2)));

// segmented butterfly: reduces a[HALF*2] over lanes, halving regs per stage
#define BSTAGE(MASK, HALF)                                        \
  { const bool hi_ = (lane & (MASK)) != 0;                        \
    _Pragma("unroll")                                             \
    for (int k_ = 0; k_ < (HALF); ++k_) {                         \
      float mine_ = hi_ ? a[k_ + (HALF)] : a[k_];                 \
      float oth_  = hi_ ? a[k_] : a[k_ + (HALF)];                 \
      a[k_] = mine_ + __shfl_xor(oth_, (MASK));                   \
    } }

// ---------------------------------------------------------------- k0: fold weights
__global__ __launch_bounds__(256) void k0_pre(const float* __restrict__ W_lin,
                                              const float* __restrict__ b_lin,
                                              const float* __restrict__ W_att,
                                              const float* __restrict__ Wa,
                                              const float* __restrict__ Wb,
                                              const float* __restrict__ Wn,
                                              const float* __restrict__ Wl,
                                              float* __restrict__ pre) {
  int t = threadIdx.x;
  for (int i = t; i < 1024; i += 256) {
    int o = i >> 6, d = i & 63;
    float sa = 0.f, sb = 0.f;
    for (int c = 0; c < 32; ++c) {
      float wl = W_lin[c * 64 + d];
      sa += Wa[o * 32 + c] * wl;
      sb += Wb[o * 32 + c] * wl;
    }
    pre[P_WAL + i] = sa;
    pre[P_WBL + i] = sb;
  }
  if (t < 64) {
    float s = 0.f;
    for (int c = 0; c < 32; ++c) s += W_att[c] * W_lin[c * 64 + t];
    pre[P_WEFF + t] = s;
  }
  if (t < 16) {
    float sa = 0.f, sb = 0.f;
    for (int c = 0; c < 32; ++c) {
      sa += Wa[t * 32 + c] * b_lin[c];
      sb += Wb[t * 32 + c] * b_lin[c];
    }
    pre[P_BWA + t] = sa;
    pre[P_BWB + t] = sb;
  }
  if (t == 0) {
    float s = 0.f;
    for (int c = 0; c < 32; ++c) s += W_att[c] * b_lin[c];
    pre[P_C0] = s;
  }
  __syncthreads();
  for (int i = t; i < 1024; i += 256) {
    int p_ = i >> 6, d = i & 63;
    float sl = 0.f, sn = 0.f;
    for (int o = 0; o < 16; ++o) {
      sl += Wl[p_ * 16 + o] * pre[P_WBL + o * 64 + d];
      sn += Wn[p_ * 16 + o] * pre[P_WAL + o * 64 + d];
    }
    pre[P_WLBL + i] = sl;
    pre[P_WNAL + i] = sn;
  }
  if (t < 16) {
    float sl = 0.f, sn = 0.f;
    for (int o = 0; o < 16; ++o) {
      sl += Wl[t * 16 + o] * pre[P_BWB + o];
      sn += Wn[t * 16 + o] * pre[P_BWA + o];
    }
    pre[P_BWL + t] = sl;
    pre[P_BWN + t] = sn;
  }
}

// ---------------------------------------------------------------- k1a: barrier-free streaming aggregation
__global__ __launch_bounds__(512, 4) void k1a(
    const float* __restrict__ xl_all, const float* __restrict__ pre,
    float* __restrict__ p_small, float* __restrict__ bigI,
    float* __restrict__ bigV) {
  __shared__ float xaggi[128][65];        // normalized intra aggregate, f32
  __shared__ float e_lds[8][16];          // per-wave e broadcast (reused per m)
  __shared__ float zrow[128];
  __shared__ float pe[5][8];
  __shared__ float scratch5[5][8][64];
  __shared__ float xagg_inter[5][64];

  const int t = threadIdx.x;
  const int b = blockIdx.x;
  const int lane = t & 63;
  const int w = t >> 6;                   // 8 waves; wave w owns rows 16w..16w+15
  const float* xl = xl_all + (size_t)b * (5 * 128 * 64);

  const float weff_r = pre[P_WEFF + lane];
  const float c0 = pre[P_C0];
  const int l4 = lane & 15;
  const int kmap4 = ((l4 & 1) << 3) | ((l4 & 2) << 1) | ((l4 & 4) >> 1) | ((l4 & 8) >> 3);

  float acc[16];
  float pi[5];
  float Z = 0.f;
  #pragma unroll
  for (int k = 0; k < 16; ++k) acc[k] = 0.f;
  #pragma unroll
  for (int m = 0; m < 5; ++m) pi[m] = 0.f;

  const float* xbase = xl + (size_t)(16 * w) * 64 + lane;
  float xA[16], xB[16];
  #pragma unroll
  for (int k = 0; k < 16; ++k) xA[k] = xbase[k * 64];

  #pragma unroll
  for (int m = 0; m < 5; ++m) {
    float* xc = (m & 1) ? xB : xA;
    float* xn = (m & 1) ? xA : xB;
    if (m < 4) {
      const float* np = xbase + (size_t)(m + 1) * 128 * 64;
      #pragma unroll
      for (int k = 0; k < 16; ++k) xn[k] = np[k * 64];
    }
    // att row-dots via segmented butterfly (16 rows over 64 lanes)
    float a[16];
    #pragma unroll
    for (int k = 0; k < 16; ++k) a[k] = xc[k] * weff_r;
    BSTAGE(1, 8) BSTAGE(2, 4) BSTAGE(4, 2) BSTAGE(8, 1)
    a[0] += __shfl_xor(a[0], 16);
    a[0] += __shfl_xor(a[0], 32);
    float e = __expf(a[0] + c0);          // no max-sub: att ~ N(0,1)
    // wave partial of sum_s e (16 rows live once per 16-lane group)
    float se = e;
    se += __shfl_xor(se, 1);
    se += __shfl_xor(se, 2);
    se += __shfl_xor(se, 4);
    se += __shfl_xor(se, 8);
    if (lane < 16) {
      e_lds[w][kmap4] = e;                // wave-local broadcast
      Z += e;                             // lane-local running denom (row kmap4)
      if (l4 == 0) pe[m][w] = se;
    }
    // read back e row (uniform b128 broadcasts)
    const float4* ep = (const float4*)&e_lds[w][0];
    float4 e0 = ep[0], e1 = ep[1], e2q = ep[2], e3 = ep[3];
    float ee[16] = {e0.x, e0.y, e0.z, e0.w, e1.x, e1.y, e1.z, e1.w,
                    e2q.x, e2q.y, e2q.z, e2q.w, e3.x, e3.y, e3.z, e3.w};
    float pim = 0.f;
    #pragma unroll
    for (int k = 0; k < 16; ++k) {
      float prod = ee[k] * xc[k];
      acc[k] += prod;
      pim += prod;
    }
    pi[m] = pim;
  }

  // publish per-wave state, then ONE barrier
  if (lane < 16) zrow[16 * w + kmap4] = Z;
  #pragma unroll
  for (int m = 0; m < 5; ++m) scratch5[m][w][lane] = pi[m];
  // normalize intra rows: need Z per row broadcast (wave-local)
  {
    const float4* zp = (const float4*)&zrow[16 * w];
    float4 z0 = zp[0], z1 = zp[1], z2 = zp[2], z3 = zp[3];
    float zz[16] = {z0.x, z0.y, z0.z, z0.w, z1.x, z1.y, z1.z, z1.w,
                    z2.x, z2.y, z2.z, z2.w, z3.x, z3.y, z3.z, z3.w};
    #pragma unroll
    for (int k = 0; k < 16; ++k) xaggi[16 * w + k][lane] = acc[k] / zz[k];
  }
  __syncthreads();

  // combine inter aggregates (normalized)
  if (t < 320) {
    int d = t & 63, mm = t >> 6;
    float s = 0.f;
    #pragma unroll
    for (int j = 0; j < 8; ++j) s += scratch5[mm][j][d];
    float sume = pe[mm][0] + pe[mm][1] + pe[mm][2] + pe[mm][3] +
                 pe[mm][4] + pe[mm][5] + pe[mm][6] + pe[mm][7];
    xagg_inter[mm][d] = s / sume;
  }
  __syncthreads();

  // phase 2: per-s projections. t = q*128 + s2; q wave-uniform -> scalar weight loads
  {
    const int q = __builtin_amdgcn_readfirstlane(w >> 1);
    const int s2 = t & 127;
    const float* Wbase = pre + ((q < 2) ? P_WBL : P_WLBL) + (q & 1) * (8 * 64);
    float acc2[8];
    #pragma unroll
    for (int r = 0; r < 8; ++r) acc2[r] = 0.f;
    #pragma unroll
    for (int c = 0; c < 64; c += 16) {
      float xa[16];
      #pragma unroll
      for (int j = 0; j < 16; ++j) xa[j] = xaggi[s2][c + j];
      #pragma unroll
      for (int r = 0; r < 8; ++r) {
        float p = acc2[r];
        #pragma unroll
        for (int j = 0; j < 16; ++j) p += xa[j] * Wbase[r * 64 + c + j];
        acc2[r] = p;
      }
    }
    const int bbase = (q < 2) ? P_BWB : P_BWL;
    float* dst = ((q < 2) ? bigI : bigV) + (size_t)b * 2048 + s2 * 16 + 8 * (q & 1);
    float4 o0, o1;
    o0.x = acc2[0] + pre[bbase + 8 * (q & 1) + 0];
    o0.y = acc2[1] + pre[bbase + 8 * (q & 1) + 1];
    o0.z = acc2[2] + pre[bbase + 8 * (q & 1) + 2];
    o0.w = acc2[3] + pre[bbase + 8 * (q & 1) + 3];
    o1.x = acc2[4] + pre[bbase + 8 * (q & 1) + 4];
    o1.y = acc2[5] + pre[bbase + 8 * (q & 1) + 5];
    o1.z = acc2[6] + pre[bbase + 8 * (q & 1) + 6];
    o1.w = acc2[7] + pre[bbase + 8 * (q & 1) + 7];
    ((float4*)dst)[0] = o0;
    ((float4*)dst)[1] = o1;
  }

  // tiny inter projections: inter2[5][16], v_inter[5][16]
  if (t < 160) {
    int o2 = t & 31, mm = t >> 5;
    const float* wr = pre + ((o2 < 16) ? (P_WAL + o2 * 64) : (P_WNAL + (o2 - 16) * 64));
    float p = 0.f;
    #pragma unroll
    for (int d = 0; d < 64; ++d) p += wr[d] * xagg_inter[mm][d];
    p += (o2 < 16) ? pre[P_BWA + o2] : pre[P_BWN + (o2 - 16)];
    float* os = p_small + (size_t)b * 160;
    if (o2 < 16) os[mm * 16 + o2] = p;
    else os[80 + mm * 16 + (o2 - 16)] = p;
  }
}

// ---------------------------------------------------------------- k1b: attention + feat + BN partials
__global__ __launch_bounds__(256, 4) void k1b(
    const float* __restrict__ xg_all, const float* __restrict__ Wc_g,
    const float* __restrict__ Wd_g, const float* __restrict__ p_small,
    const float* __restrict__ bigI, const float* __restrict__ bigV,
    float* __restrict__ out, float* __restrict__ bn_part) {
  __shared__ float comb[256][18];
  __shared__ float part[4][32];

  const int t = threadIdx.x;
  const int b = blockIdx.x;
  const int n = t & 127;
  const int sh = t >> 7;
  const int w = t >> 6;
  const int lane = t & 63;
  const int kmap = ((lane & 1) << 4) | ((lane & 2) << 2) | (lane & 4) |
                   ((lane >> 2) & 2) | ((lane >> 4) & 1);
  const float* xg = xg_all + (size_t)b * (128 * 32);

  // xlog[n][0..15]
  float xc[32];
  const float4* xr = (const float4*)(xg + n * 32);
  #pragma unroll
  for (int q = 0; q < 8; ++q) {
    float4 v = xr[q];
    xc[4 * q] = v.x; xc[4 * q + 1] = v.y; xc[4 * q + 2] = v.z; xc[4 * q + 3] = v.w;
  }
  float xlog[16];
  #pragma unroll
  for (int o = 0; o < 16; ++o) {
    float p = 0.f;
    #pragma unroll
    for (int c = 0; c < 32; ++c) p += Wc_g[o * 32 + c] * xc[c];
    xlog[o] = p;
  }
  f32x2 xl2[8];
  #pragma unroll
  for (int q = 0; q < 8; ++q) { xl2[q].x = xlog[2 * q]; xl2[q].y = xlog[2 * q + 1]; }

  // softmax-weighted sum over this thread's s-half (wave-uniform rows -> scalar loads)
  const int shu = __builtin_amdgcn_readfirstlane(sh);
  const float* Ib = bigI + (size_t)b * 2048 + (size_t)shu * 1024;
  const float* Vb = bigV + (size_t)b * 2048 + (size_t)shu * 1024;
  float sum = 0.f;
  f32x2 fa2[8];
  #pragma unroll
  for (int j = 0; j < 8; ++j) fa2[j] = (f32x2)0.f;
  for (int i = 0; i < 64; ++i) {
    const f32x2* rI = (const f32x2*)(Ib + i * 16);
    f32x2 p2 = (f32x2)0.f;
    #pragma unroll
    for (int q = 0; q < 8; ++q) p2 += xl2[q] * rI[q];
    float e = __expf(p2.x + p2.y);        // no max-sub
    sum += e;
    f32x2 e2; e2.x = e; e2.y = e;
    const f32x2* rV = (const f32x2*)(Vb + i * 16);
    #pragma unroll
    for (int q = 0; q < 8; ++q) fa2[q] += e2 * rV[q];
  }
  // merge the two halves via LDS (no max tracking -> plain sums)
  comb[t][0] = sum;
  #pragma unroll
  for (int j = 0; j < 8; ++j) { comb[t][1 + 2 * j] = fa2[j].x; comb[t][2 + 2 * j] = fa2[j].y; }
  __syncthreads();
  const int pt = t ^ 128;
  float inv = 1.f / (sum + comb[pt][0]);
  float fint[16];
  #pragma unroll
  for (int j = 0; j < 8; ++j) {
    fint[2 * j]     = (fa2[j].x + comb[pt][1 + 2 * j]) * inv;
    fint[2 * j + 1] = (fa2[j].y + comb[pt][2 + 2 * j]) * inv;
  }

  // f_inter (5-way softmax), duplicated by both partners
  const float* sm = p_small + (size_t)b * 160;
  float L[5], mx3 = -1e30f;
  #pragma unroll
  for (int mm = 0; mm < 5; ++mm) {
    float p = 0.f;
    #pragma unroll
    for (int o = 0; o < 16; ++o) p += xlog[o] * sm[mm * 16 + o];
    L[mm] = p;
    mx3 = fmaxf(mx3, p);
  }
  float sum3 = 0.f;
  #pragma unroll
  for (int mm = 0; mm < 5; ++mm) { L[mm] = __expf(L[mm] - mx3); sum3 += L[mm]; }
  float inv3 = 1.f / sum3;
  float fi[16];
  #pragma unroll
  for (int j = 0; j < 16; ++j) {
    float p = 0.f;
    #pragma unroll
    for (int mm = 0; mm < 5; ++mm) p += L[mm] * sm[80 + mm * 16 + j];
    fi[j] = p * inv3;
  }

  // feat for o in [16*sh, 16*sh+16)
  float feat[16];
  #pragma unroll
  for (int j = 0; j < 16; ++j) {
    int o = 16 * sh + j;
    float p = 0.f;
    #pragma unroll
    for (int c = 0; c < 16; ++c) p += Wd_g[o * 32 + c] * fi[c];
    #pragma unroll
    for (int c = 0; c < 16; ++c) p += Wd_g[o * 32 + 16 + c] * fint[c];
    feat[j] = p;
  }
  float* op = out + ((size_t)b * 128 + n) * 32 + 16 * sh;
  #pragma unroll
  for (int q = 0; q < 4; ++q)
    ((float4*)op)[q] = make_float4(feat[4 * q], feat[4 * q + 1], feat[4 * q + 2], feat[4 * q + 3]);

  // BN partials: butterfly-reduce 32 values (s1[16], s2[16]) over 64 lanes
  {
    float a[32];
    #pragma unroll
    for (int j = 0; j < 16; ++j) { a[j] = feat[j]; a[16 + j] = feat[j] * feat[j]; }
    BSTAGE(1, 16) BSTAGE(2, 8) BSTAGE(4, 4) BSTAGE(8, 2) BSTAGE(16, 1)
    a[0] += __shfl_xor(a[0], 32);
    if (lane < 32) part[w][kmap] = a[0];
  }
  __syncthreads();
  if (t < 64) {
    int c = t & 31, q = t >> 5;
    float v;
    if (c < 16) v = part[0][q * 16 + c] + part[1][q * 16 + c];
    else        v = part[2][q * 16 + (c - 16)] + part[3][q * 16 + (c - 16)];
    bn_part[(size_t)b * 64 + q * 32 + c] = v;
  }
}

// ---------------------------------------------------------------- k2: BN coefficients
__global__ __launch_bounds__(256) void k2_stats(const float* __restrict__ bn_part,
                                                const float* __restrict__ gamma,
                                                const float* __restrict__ beta,
                                                float* __restrict__ coef) {
  __shared__ float sc[4][64];
  int t = threadIdx.x;
  int c = t & 63, q = t >> 6;
  float s = 0.f;
  for (int b = q; b < NB; b += 4) s += bn_part[b * 64 + c];
  sc[q][c] = s;
  __syncthreads();
  if (t < 64) sc[0][t] = sc[0][t] + sc[1][t] + sc[2][t] + sc[3][t];
  __syncthreads();
  if (t < 32) {
    const float inv = 1.f / (float)(NB * 128);
    float mean = sc[0][t] * inv;
    float var = sc[0][t + 32] * inv - mean * mean;
    float scl = gamma[t] * rsqrtf(var + 1e-5f);
    coef[t] = scl;
    coef[32 + t] = beta[t] - mean * scl;
  }
}

// ---------------------------------------------------------------- k3: BN apply + residual + leaky (in place)
__global__ __launch_bounds__(256) void k3_final(const float* __restrict__ xg,
                                                float* __restrict__ out,
                                                const float* __restrict__ coef) {
  __shared__ float s_c[64];
  if (threadIdx.x < 64) s_c[threadIdx.x] = coef[threadIdx.x];
  __syncthreads();
  size_t i4 = (size_t)blockIdx.x * 256 + threadIdx.x;
  float4 f = ((const float4*)out)[i4];
  float4 x = ((const float4*)xg)[i4];
  int c = (int)((i4 * 4) & 31);
  float4 r;
  r.x = x.x + f.x * s_c[c + 0] + s_c[32 + c + 0];
  r.y = x.y + f.y * s_c[c + 1] + s_c[32 + c + 1];
  r.z = x.z + f.z * s_c[c + 2] + s_c[32 + c + 2];
  r.w = x.w + f.w * s_c[c + 3] + s_c[32 + c + 3];
  r.x = r.x >= 0.f ? r.x : 0.2f * r.x;
  r.y = r.y >= 0.f ? r.y : 0.2f * r.y;
  r.z = r.z >= 0.f ? r.z : 0.2f * r.z;
  r.w = r.w >= 0.f ? r.w : 0.2f * r.w;
  ((float4*)out)[i4] = r;
}

// ----------------------------------------------------------------
extern "C" void kernel_launch(void* const* d_in, const int* in_sizes, int n_in,
                              void* d_out, int out_size, void* d_ws, size_t ws_size,
                              hipStream_t stream) {
  const float* xg    = (const float*)d_in[0];
  const float* xl    = (const float*)d_in[1];
  const float* W_lin = (const float*)d_in[2];
  const float* b_lin = (const float*)d_in[3];
  const float* W_att = (const float*)d_in[4];
  const float* Wa    = (const float*)d_in[5];
  const float* Wb    = (const float*)d_in[6];
  const float* Wc    = (const float*)d_in[7];
  const float* Wn    = (const float*)d_in[8];
  const float* Wl    = (const float*)d_in[9];
  const float* Wd    = (const float*)d_in[10];
  const float* gamma = (const float*)d_in[11];
  const float* beta  = (const float*)d_in[12];
  float* out = (float*)d_out;
  float* ws = (float*)d_ws;
  float* pre = ws;
  float* bn_part = ws + WS_BNPART;
  float* coef = ws + WS_COEF;
  float* p_small = ws + WS_SMALL;
  float* bigI = ws + WS_BIG_I;
  float* bigV = ws + WS_BIG_V;

  hipLaunchKernelGGL(k0_pre, dim3(1), dim3(256), 0, stream,
                     W_lin, b_lin, W_att, Wa, Wb, Wn, Wl, pre);
  hipLaunchKernelGGL(k1a, dim3(NB), dim3(512), 0, stream, xl, pre, p_small, bigI, bigV);
  hipLaunchKernelGGL(k1b, dim3(NB), dim3(256), 0, stream,
                     xg, Wc, Wd, p_small, bigI, bigV, out, bn_part);
  hipLaunchKernelGGL(k2_stats, dim3(1), dim3(256), 0, stream, bn_part, gamma, beta, coef);
  hipLaunchKernelGGL(k3_final, dim3(8192), dim3(256), 0, stream, xg, out, coef);
}

// Round 4
// 197.174 us; speedup vs baseline: 2.4371x; 2.4371x over previous
//
#include <hip/hip_runtime.h>
#include <math.h>

#define NB 2048
typedef float f32x4 __attribute__((ext_vector_type(4)));

// pre[] float offsets (folded weights)
#define P_WAL 0
#define P_WBL 1024
#define P_WLBL 2048
#define P_WNAL 3072
#define P_WEFF 4096
#define P_BWA 4160
#define P_BWB 4176
#define P_BWL 4192
#define P_BWN 4208
#define P_C0  4224

// ws float offsets
#define WS_BNPART 4352
#define WS_COEF   135424
#define WS_SMALL  135488
#define WS_BIG_I  463168                  // [2048][2048] f32: intra2T rows [s][16]
#define WS_BIG_V  (463168 + 4194304)      // [2048][2048] f32: v_intra rows [s][16]

// segmented butterfly: reduces a[HALF*2] over lanes, halving regs per stage
#define BSTAGE(MASK, HALF)                                        \
  { const bool hi_ = (lane & (MASK)) != 0;                        \
    _Pragma("unroll")                                             \
    for (int k_ = 0; k_ < (HALF); ++k_) {                         \
      float mine_ = hi_ ? a[k_ + (HALF)] : a[k_];                 \
      float oth_  = hi_ ? a[k_] : a[k_ + (HALF)];                 \
      a[k_] = mine_ + __shfl_xor(oth_, (MASK));                   \
    } }

// ---------------------------------------------------------------- k0: fold weights
__global__ __launch_bounds__(256) void k0_pre(const float* __restrict__ W_lin,
                                              const float* __restrict__ b_lin,
                                              const float* __restrict__ W_att,
                                              const float* __restrict__ Wa,
                                              const float* __restrict__ Wb,
                                              const float* __restrict__ Wn,
                                              const float* __restrict__ Wl,
                                              float* __restrict__ pre) {
  int t = threadIdx.x;
  for (int i = t; i < 1024; i += 256) {
    int o = i >> 6, d = i & 63;
    float sa = 0.f, sb = 0.f;
    for (int c = 0; c < 32; ++c) {
      float wl = W_lin[c * 64 + d];
      sa += Wa[o * 32 + c] * wl;
      sb += Wb[o * 32 + c] * wl;
    }
    pre[P_WAL + i] = sa;
    pre[P_WBL + i] = sb;
  }
  if (t < 64) {
    float s = 0.f;
    for (int c = 0; c < 32; ++c) s += W_att[c] * W_lin[c * 64 + t];
    pre[P_WEFF + t] = s;
  }
  if (t < 16) {
    float sa = 0.f, sb = 0.f;
    for (int c = 0; c < 32; ++c) {
      sa += Wa[t * 32 + c] * b_lin[c];
      sb += Wb[t * 32 + c] * b_lin[c];
    }
    pre[P_BWA + t] = sa;
    pre[P_BWB + t] = sb;
  }
  if (t == 0) {
    float s = 0.f;
    for (int c = 0; c < 32; ++c) s += W_att[c] * b_lin[c];
    pre[P_C0] = s;
  }
  __syncthreads();
  for (int i = t; i < 1024; i += 256) {
    int p_ = i >> 6, d = i & 63;
    float sl = 0.f, sn = 0.f;
    for (int o = 0; o < 16; ++o) {
      sl += Wl[p_ * 16 + o] * pre[P_WBL + o * 64 + d];
      sn += Wn[p_ * 16 + o] * pre[P_WAL + o * 64 + d];
    }
    pre[P_WLBL + i] = sl;
    pre[P_WNAL + i] = sn;
  }
  if (t < 16) {
    float sl = 0.f, sn = 0.f;
    for (int o = 0; o < 16; ++o) {
      sl += Wl[t * 16 + o] * pre[P_BWB + o];
      sn += Wn[t * 16 + o] * pre[P_BWA + o];
    }
    pre[P_BWL + t] = sl;
    pre[P_BWN + t] = sn;
  }
}

// ---------------------------------------------------------------- k1a: streaming aggregation, float4 lanes, no spills
__global__ __launch_bounds__(512, 1) void k1a(
    const float* __restrict__ xl_all, const float* __restrict__ pre,
    float* __restrict__ p_small, float* __restrict__ bigI,
    float* __restrict__ bigV) {
  __shared__ __align__(16) float xaggi[128 * 68];   // pad 68: uniform bank spread
  __shared__ f32x4 scratch5[5][8][16];              // per-m, per-wave inter partials
  __shared__ float pe[5][8];
  __shared__ float xagg_inter[5][64];

  const int t = threadIdx.x;
  const int b = blockIdx.x;
  const int lane = t & 63;
  const int w = t >> 6;                 // 8 waves; wave owns rows 16w..16w+15
  const int q = lane >> 4;              // quadrant -> row offset within group of 4
  const int i16 = lane & 15;            // d-chunk (4 floats)

  const float* xl = xl_all + (size_t)b * (5 * 128 * 64);
  const f32x4 weff4 = ((const f32x4*)(pre + P_WEFF))[i16];
  const float c0 = pre[P_C0];

  // row(k) = 16w + 4k + q; float offset = row*64 + 4*i16
  const float* xb = xl + (size_t)(16 * w + q) * 64 + 4 * i16;

  f32x4 xA[4], xB[4], acc[4];
  float Zk[4];
  #pragma unroll
  for (int k = 0; k < 4; ++k) {
    acc[k] = (f32x4)0.f;
    Zk[k] = 0.f;
    xA[k] = *(const f32x4*)(xb + k * 256);
  }

  #pragma unroll
  for (int m = 0; m < 5; ++m) {
    f32x4* xc = (m & 1) ? xB : xA;
    f32x4* xn = (m & 1) ? xA : xB;
    if (m < 4) {
      const float* np = xb + (size_t)(m + 1) * 8192;
      #pragma unroll
      for (int k = 0; k < 4; ++k) xn[k] = *(const f32x4*)(np + k * 256);
    }
    // row dots: partial dot4 then butterfly over the 16-lane group
    float a0, a1, a2, a3;
    {
      f32x4 p0 = xc[0] * weff4, p1 = xc[1] * weff4, p2 = xc[2] * weff4, p3 = xc[3] * weff4;
      a0 = p0.x + p0.y + p0.z + p0.w;
      a1 = p1.x + p1.y + p1.z + p1.w;
      a2 = p2.x + p2.y + p2.z + p2.w;
      a3 = p3.x + p3.y + p3.z + p3.w;
    }
    #pragma unroll
    for (int mask = 1; mask <= 8; mask <<= 1) {
      a0 += __shfl_xor(a0, mask);
      a1 += __shfl_xor(a1, mask);
      a2 += __shfl_xor(a2, mask);
      a3 += __shfl_xor(a3, mask);
    }
    float e0 = __expf(a0 + c0), e1 = __expf(a1 + c0);
    float e2 = __expf(a2 + c0), e3 = __expf(a3 + c0);
    Zk[0] += e0; Zk[1] += e1; Zk[2] += e2; Zk[3] += e3;
    f32x4 pim;
    {
      f32x4 pr0 = e0 * xc[0];
      f32x4 pr1 = e1 * xc[1];
      f32x4 pr2 = e2 * xc[2];
      f32x4 pr3 = e3 * xc[3];
      acc[0] += pr0; acc[1] += pr1; acc[2] += pr2; acc[3] += pr3;
      pim = pr0 + pr1 + pr2 + pr3;
    }
    float se = e0 + e1 + e2 + e3;
    #pragma unroll
    for (int mask = 16; mask <= 32; mask <<= 1) {
      pim.x += __shfl_xor(pim.x, mask);
      pim.y += __shfl_xor(pim.y, mask);
      pim.z += __shfl_xor(pim.z, mask);
      pim.w += __shfl_xor(pim.w, mask);
      se += __shfl_xor(se, mask);
    }
    if (lane < 16) {
      scratch5[m][w][i16] = pim;
      if (i16 == 0) pe[m][w] = se;
    }
  }

  // normalize intra rows (thread-local!) and write transposable LDS copy
  #pragma unroll
  for (int k = 0; k < 4; ++k) {
    float invz = 1.f / Zk[k];
    f32x4 v = acc[k] * invz;
    int r = 16 * w + 4 * k + q;
    *(f32x4*)&xaggi[r * 68 + 4 * i16] = v;
  }
  __syncthreads();

  // combine inter aggregates across waves, normalize
  if (t < 320) {
    int mm = t >> 6, d = t & 63;
    const float* sp = (const float*)&scratch5[mm][0][0];
    float s = 0.f;
    #pragma unroll
    for (int j = 0; j < 8; ++j) s += sp[j * 64 + d];
    float sume = pe[mm][0] + pe[mm][1] + pe[mm][2] + pe[mm][3] +
                 pe[mm][4] + pe[mm][5] + pe[mm][6] + pe[mm][7];
    xagg_inter[mm][d] = s / sume;
  }
  __syncthreads();

  // phase 2a: per-s projections (intra2 -> bigI, v_intra -> bigV)
  {
    const int q2 = __builtin_amdgcn_readfirstlane(t >> 7);   // 0..3, wave-uniform
    const int s2 = t & 127;
    const float* Wbase = pre + ((q2 < 2) ? P_WBL : P_WLBL) + (q2 & 1) * 512;
    const float* xrow = &xaggi[s2 * 68];
    float acc2[8];
    #pragma unroll
    for (int r = 0; r < 8; ++r) acc2[r] = 0.f;
    #pragma unroll
    for (int c = 0; c < 64; c += 4) {
      f32x4 xa = *(const f32x4*)(xrow + c);
      #pragma unroll
      for (int r = 0; r < 8; ++r)
        acc2[r] += xa.x * Wbase[r * 64 + c] + xa.y * Wbase[r * 64 + c + 1] +
                   xa.z * Wbase[r * 64 + c + 2] + xa.w * Wbase[r * 64 + c + 3];
    }
    const int bb = ((q2 < 2) ? P_BWB : P_BWL) + (q2 & 1) * 8;
    float* dst = ((q2 < 2) ? bigI : bigV) + (size_t)b * 2048 + s2 * 16 + (q2 & 1) * 8;
    f32x4 o0, o1;
    o0.x = acc2[0] + pre[bb + 0];
    o0.y = acc2[1] + pre[bb + 1];
    o0.z = acc2[2] + pre[bb + 2];
    o0.w = acc2[3] + pre[bb + 3];
    o1.x = acc2[4] + pre[bb + 4];
    o1.y = acc2[5] + pre[bb + 5];
    o1.z = acc2[6] + pre[bb + 6];
    o1.w = acc2[7] + pre[bb + 7];
    *(f32x4*)dst = o0;
    *(f32x4*)(dst + 4) = o1;
  }

  // tiny inter projections: inter2[5][16], v_inter[5][16]
  if (t < 160) {
    int o2 = t & 31, mm = t >> 5;
    const float* wr = pre + ((o2 < 16) ? (P_WAL + o2 * 64) : (P_WNAL + (o2 - 16) * 64));
    float p = 0.f;
    #pragma unroll
    for (int d = 0; d < 64; ++d) p += wr[d] * xagg_inter[mm][d];
    p += (o2 < 16) ? pre[P_BWA + o2] : pre[P_BWN + (o2 - 16)];
    float* os = p_small + (size_t)b * 160;
    if (o2 < 16) os[mm * 16 + o2] = p;
    else os[80 + mm * 16 + (o2 - 16)] = p;
  }
}

// ---------------------------------------------------------------- k1b: attention + feat + BN partials (LDS-staged slabs)
__global__ __launch_bounds__(128, 1) void k1b(
    const float* __restrict__ xg_all, const float* __restrict__ Wc_g,
    const float* __restrict__ Wd_g, const float* __restrict__ p_small,
    const float* __restrict__ bigI, const float* __restrict__ bigV,
    float* __restrict__ out, float* __restrict__ bn_part) {
  __shared__ f32x4 slabI[128][4];
  __shared__ f32x4 slabV[128][4];
  __shared__ float part1[2][32];
  __shared__ float part2[2][32];

  const int t = threadIdx.x;             // = n
  const int b = blockIdx.x;
  const int lane = t & 63;
  const int w = t >> 6;
  const int kmap = ((lane & 1) << 4) | ((lane & 2) << 2) | (lane & 4) |
                   ((lane >> 2) & 2) | ((lane >> 4) & 1);

  // stage I/V slabs (16 KB, coalesced)
  const f32x4* gI = (const f32x4*)(bigI + (size_t)b * 2048);
  const f32x4* gV = (const f32x4*)(bigV + (size_t)b * 2048);
  #pragma unroll
  for (int j = 0; j < 4; ++j) {
    ((f32x4*)slabI)[t + 128 * j] = gI[t + 128 * j];
    ((f32x4*)slabV)[t + 128 * j] = gV[t + 128 * j];
  }

  // xlog[n][0..15] = Wc . xg[n]
  const f32x4* xgr = (const f32x4*)(xg_all + ((size_t)b * 128 + t) * 32);
  f32x4 xv[8];
  #pragma unroll
  for (int j = 0; j < 8; ++j) xv[j] = xgr[j];
  f32x4 xl4[4];
  #pragma unroll
  for (int o4 = 0; o4 < 4; ++o4) {
    f32x4 r;
    #pragma unroll
    for (int jj = 0; jj < 4; ++jj) {
      const int o = o4 * 4 + jj;
      f32x4 s = (f32x4)0.f;
      #pragma unroll
      for (int j = 0; j < 8; ++j) s += xv[j] * *(const f32x4*)(Wc_g + o * 32 + 4 * j);
      r[jj] = s.x + s.y + s.z + s.w;
    }
    xl4[o4] = r;
  }
  __syncthreads();

  // f_intra: 128-way softmax-weighted sum (no max-sub; logits O(10))
  float sum = 0.f;
  f32x4 fa[4];
  #pragma unroll
  for (int j = 0; j < 4; ++j) fa[j] = (f32x4)0.f;
  for (int i = 0; i < 128; ++i) {
    f32x4 d4 = xl4[0] * slabI[i][0] + xl4[1] * slabI[i][1] +
               xl4[2] * slabI[i][2] + xl4[3] * slabI[i][3];
    float e = __expf(d4.x + d4.y + d4.z + d4.w);
    sum += e;
    #pragma unroll
    for (int j = 0; j < 4; ++j) fa[j] += e * slabV[i][j];
  }
  const float inv = 1.f / sum;
  f32x4 fin[4];
  #pragma unroll
  for (int j = 0; j < 4; ++j) fin[j] = fa[j] * inv;

  // f_inter: 5-way softmax
  const float* sm = p_small + (size_t)b * 160;
  float L[5], mx3 = -1e30f;
  #pragma unroll
  for (int mm = 0; mm < 5; ++mm) {
    float p = 0.f;
    #pragma unroll
    for (int o4 = 0; o4 < 4; ++o4) {
      #pragma unroll
      for (int jj = 0; jj < 4; ++jj) p += xl4[o4][jj] * sm[mm * 16 + o4 * 4 + jj];
    }
    L[mm] = p;
    mx3 = fmaxf(mx3, p);
  }
  float sum3 = 0.f;
  #pragma unroll
  for (int mm = 0; mm < 5; ++mm) { L[mm] = __expf(L[mm] - mx3); sum3 += L[mm]; }
  const float inv3 = 1.f / sum3;
  f32x4 fi[4];
  #pragma unroll
  for (int o4 = 0; o4 < 4; ++o4) {
    f32x4 r;
    #pragma unroll
    for (int jj = 0; jj < 4; ++jj) {
      float p = 0.f;
      #pragma unroll
      for (int mm = 0; mm < 5; ++mm) p += L[mm] * sm[80 + mm * 16 + o4 * 4 + jj];
      r[jj] = p * inv3;
    }
    fi[o4] = r;
  }

  // feat[o] = Wd[o][0:16].fi + Wd[o][16:32].fin
  f32x4 feat[8];
  #pragma unroll
  for (int o4 = 0; o4 < 8; ++o4) {
    f32x4 r;
    #pragma unroll
    for (int jj = 0; jj < 4; ++jj) {
      const int o = o4 * 4 + jj;
      f32x4 s = (f32x4)0.f;
      #pragma unroll
      for (int j = 0; j < 4; ++j) {
        s += fi[j]  * *(const f32x4*)(Wd_g + o * 32 + 4 * j);
        s += fin[j] * *(const f32x4*)(Wd_g + o * 32 + 16 + 4 * j);
      }
      r[jj] = s.x + s.y + s.z + s.w;
    }
    feat[o4] = r;
  }
  f32x4* op = (f32x4*)(out + ((size_t)b * 128 + t) * 32);
  #pragma unroll
  for (int o4 = 0; o4 < 8; ++o4) op[o4] = feat[o4];

  // BN partials: two 32-value butterfly reductions over 64 lanes
  {
    float a[32];
    #pragma unroll
    for (int o = 0; o < 32; ++o) a[o] = feat[o >> 2][o & 3];
    BSTAGE(1, 16) BSTAGE(2, 8) BSTAGE(4, 4) BSTAGE(8, 2) BSTAGE(16, 1)
    a[0] += __shfl_xor(a[0], 32);
    if (lane < 32) part1[w][kmap] = a[0];
  }
  {
    float a[32];
    #pragma unroll
    for (int o = 0; o < 32; ++o) { float v = feat[o >> 2][o & 3]; a[o] = v * v; }
    BSTAGE(1, 16) BSTAGE(2, 8) BSTAGE(4, 4) BSTAGE(8, 2) BSTAGE(16, 1)
    a[0] += __shfl_xor(a[0], 32);
    if (lane < 32) part2[w][kmap] = a[0];
  }
  __syncthreads();
  if (t < 64) {
    int c = t & 31, h = t >> 5;
    float v = h ? (part2[0][c] + part2[1][c]) : (part1[0][c] + part1[1][c]);
    bn_part[(size_t)b * 64 + h * 32 + c] = v;
  }
}

// ---------------------------------------------------------------- k2: BN coefficients (one block per channel)
__global__ __launch_bounds__(256, 1) void k2_stats(const float* __restrict__ bn_part,
                                                   const float* __restrict__ gamma,
                                                   const float* __restrict__ beta,
                                                   float* __restrict__ coef) {
  __shared__ float red[2][4];
  const int c = blockIdx.x;              // 0..31
  const int t = threadIdx.x;
  const int lane = t & 63, w = t >> 6;
  float s1 = 0.f, s2 = 0.f;
  for (int bb = t; bb < NB; bb += 256) {
    s1 += bn_part[(size_t)bb * 64 + c];
    s2 += bn_part[(size_t)bb * 64 + c + 32];
  }
  #pragma unroll
  for (int mask = 1; mask <= 32; mask <<= 1) {
    s1 += __shfl_xor(s1, mask);
    s2 += __shfl_xor(s2, mask);
  }
  if (lane == 0) { red[0][w] = s1; red[1][w] = s2; }
  __syncthreads();
  if (t == 0) {
    float S1 = red[0][0] + red[0][1] + red[0][2] + red[0][3];
    float S2 = red[1][0] + red[1][1] + red[1][2] + red[1][3];
    const float inv = 1.f / (float)(NB * 128);
    float mean = S1 * inv;
    float var = S2 * inv - mean * mean;
    float scl = gamma[c] * rsqrtf(var + 1e-5f);
    coef[c] = scl;
    coef[32 + c] = beta[c] - mean * scl;
  }
}

// ---------------------------------------------------------------- k3: BN apply + residual + leaky (in place)
__global__ __launch_bounds__(256) void k3_final(const float* __restrict__ xg,
                                                float* __restrict__ out,
                                                const float* __restrict__ coef) {
  __shared__ float s_c[64];
  if (threadIdx.x < 64) s_c[threadIdx.x] = coef[threadIdx.x];
  __syncthreads();
  size_t i4 = (size_t)blockIdx.x * 256 + threadIdx.x;
  float4 f = ((const float4*)out)[i4];
  float4 x = ((const float4*)xg)[i4];
  int c = (int)((i4 * 4) & 31);
  float4 r;
  r.x = x.x + f.x * s_c[c + 0] + s_c[32 + c + 0];
  r.y = x.y + f.y * s_c[c + 1] + s_c[32 + c + 1];
  r.z = x.z + f.z * s_c[c + 2] + s_c[32 + c + 2];
  r.w = x.w + f.w * s_c[c + 3] + s_c[32 + c + 3];
  r.x = r.x >= 0.f ? r.x : 0.2f * r.x;
  r.y = r.y >= 0.f ? r.y : 0.2f * r.y;
  r.z = r.z >= 0.f ? r.z : 0.2f * r.z;
  r.w = r.w >= 0.f ? r.w : 0.2f * r.w;
  ((float4*)out)[i4] = r;
}

// ----------------------------------------------------------------
extern "C" void kernel_launch(void* const* d_in, const int* in_sizes, int n_in,
                              void* d_out, int out_size, void* d_ws, size_t ws_size,
                              hipStream_t stream) {
  const float* xg    = (const float*)d_in[0];
  const float* xl    = (const float*)d_in[1];
  const float* W_lin = (const float*)d_in[2];
  const float* b_lin = (const float*)d_in[3];
  const float* W_att = (const float*)d_in[4];
  const float* Wa    = (const float*)d_in[5];
  const float* Wb    = (const float*)d_in[6];
  const float* Wc    = (const float*)d_in[7];
  const float* Wn    = (const float*)d_in[8];
  const float* Wl    = (const float*)d_in[9];
  const float* Wd    = (const float*)d_in[10];
  const float* gamma = (const float*)d_in[11];
  const float* beta  = (const float*)d_in[12];
  float* out = (float*)d_out;
  float* ws = (float*)d_ws;
  float* pre = ws;
  float* bn_part = ws + WS_BNPART;
  float* coef = ws + WS_COEF;
  float* p_small = ws + WS_SMALL;
  float* bigI = ws + WS_BIG_I;
  float* bigV = ws + WS_BIG_V;

  hipLaunchKernelGGL(k0_pre, dim3(1), dim3(256), 0, stream,
                     W_lin, b_lin, W_att, Wa, Wb, Wn, Wl, pre);
  hipLaunchKernelGGL(k1a, dim3(NB), dim3(512), 0, stream, xl, pre, p_small, bigI, bigV);
  hipLaunchKernelGGL(k1b, dim3(NB), dim3(128), 0, stream,
                     xg, Wc, Wd, p_small, bigI, bigV, out, bn_part);
  hipLaunchKernelGGL(k2_stats, dim3(32), dim3(256), 0, stream, bn_part, gamma, beta, coef);
  hipLaunchKernelGGL(k3_final, dim3(8192), dim3(256), 0, stream, xg, out, coef);
}